// Round 4
// baseline (315.524 us; speedup 1.0000x reference)
//
#include <hip/hip_runtime.h>

typedef short bf16x8 __attribute__((ext_vector_type(8)));
typedef float f32x4 __attribute__((ext_vector_type(4)));
typedef unsigned short u16x8 __attribute__((ext_vector_type(8)));

static __device__ __forceinline__ unsigned short f2bf(float f) {
  unsigned int x = __builtin_bit_cast(unsigned int, f);
  x += 0x7FFFu + ((x >> 16) & 1u);   // RNE
  return (unsigned short)(x >> 16);
}
// pack two floats' bf16 (round-half-up) into one u32 (lo=a, hi=b)
static __device__ __forceinline__ unsigned int pk2bf(float a, float b) {
  unsigned int ia = __builtin_bit_cast(unsigned int, a) + 0x8000u;
  unsigned int ib = __builtin_bit_cast(unsigned int, b) + 0x8000u;
  return __builtin_amdgcn_perm(ib, ia, 0x07060302u);
}
// HW packed f32->bf16 (RNE), 1 instruction for 2 values: lo=a, hi=b
static __device__ __forceinline__ unsigned int cvtpk(float a, float b) {
  unsigned int r;
  asm("v_cvt_pk_bf16_f32 %0, %1, %2" : "=v"(r) : "v"(a), "v"(b));
  return r;
}
// async 16B global -> LDS
static __device__ __forceinline__ void gl2lds16(const unsigned short* g, unsigned short* l) {
  __builtin_amdgcn_global_load_lds(
      (const __attribute__((address_space(1))) unsigned int*)g,
      (__attribute__((address_space(3))) unsigned int*)l, 16, 0, 0);
}

// ---------------- fused q/k/v fp32 -> bf16 (8 elems/thread) ----------------
__global__ __launch_bounds__(256) void cvt3(const float* __restrict__ q, const float* __restrict__ k,
                                            const float* __restrict__ v,
                                            unsigned short* __restrict__ qo, unsigned short* __restrict__ ko,
                                            unsigned short* __restrict__ vo) {
  const float* src = (blockIdx.y == 0) ? q : (blockIdx.y == 1) ? k : v;
  unsigned short* dst = (blockIdx.y == 0) ? qo : (blockIdx.y == 1) ? ko : vo;
  int i = (blockIdx.x * 256 + threadIdx.x) * 8;
  float4 a = *(const float4*)(src + i);
  float4 b = *(const float4*)(src + i + 4);
  uint4 pk;
  pk.x = pk2bf(a.x, a.y); pk.y = pk2bf(a.z, a.w);
  pk.z = pk2bf(b.x, b.y); pk.w = pk2bf(b.z, b.w);
  *(uint4*)(dst + i) = pk;
}

// ------- 4x W [512k][512n] f32 -> WT [4][512n][512k] bf16 (z selects matrix) -------
__global__ __launch_bounds__(256) void wtrans4(const float* __restrict__ Wq, const float* __restrict__ Wk,
                                               const float* __restrict__ Wv, const float* __restrict__ Wo,
                                               unsigned short* __restrict__ WT) {
  __shared__ __align__(16) float T[64 * 68];
  const int z = blockIdx.z;
  const float* W = (z == 0) ? Wq : (z == 1) ? Wk : (z == 2) ? Wv : Wo;
  unsigned short* out = WT + (size_t)z * 512 * 512;
  const int k0 = blockIdx.x * 64, n0 = blockIdx.y * 64;
  const int tid = threadIdx.x;
#pragma unroll
  for (int i = 0; i < 4; ++i) {
    int chunk = i * 256 + tid;
    int row = chunk >> 4, fc = chunk & 15;
    *(float4*)(T + row * 68 + fc * 4) =
        *(const float4*)(W + (size_t)(k0 + row) * 512 + n0 + fc * 4);
  }
  __syncthreads();
#pragma unroll
  for (int i = 0; i < 2; ++i) {
    int chunk = i * 256 + tid;
    int nr = chunk >> 3, kc = chunk & 7;
    u16x8 v;
#pragma unroll
    for (int j = 0; j < 8; ++j) v[j] = f2bf(T[(kc * 8 + j) * 68 + nr]);
    *(u16x8*)(out + (size_t)(n0 + nr) * 512 + k0 + kc * 8) = v;
  }
}

// ---- fused QKV GEMM: C[8192][1536] = [q|k|v] proj. 128x64 tile, BK=64, async dbuf. ----
__global__ __launch_bounds__(256) void gemm_qkv(const unsigned short* __restrict__ Aq,
                                                const unsigned short* __restrict__ Ak,
                                                const unsigned short* __restrict__ Av,
                                                const unsigned short* __restrict__ Bt,
                                                unsigned short* __restrict__ C,
                                                float qscale) {
  __shared__ __align__(16) unsigned short Abuf[2][128 * 64];
  __shared__ __align__(16) unsigned short Bbuf[2][64 * 64];
  const int K = 512, LDC = 1536;
  const unsigned short* A = (blockIdx.y < 8) ? Aq : (blockIdx.y < 16) ? Ak : Av;
  const float scale = (blockIdx.y < 8) ? qscale : 1.0f;
  const int tid = threadIdx.x;
  const int wid = tid >> 6, lane = tid & 63, quad = lane >> 4, li = lane & 15;
  const int bm = blockIdx.x * 128, bn = blockIdx.y * 64;
  const int wm = wid * 32;
  const unsigned short* ga[4]; int oa[4];
  const unsigned short* gb[2]; int ob[2];
#pragma unroll
  for (int i = 0; i < 4; ++i) {
    int lam = i * 256 + wid * 64 + lane;
    int r = lam >> 3, c = (lam & 7) ^ (r & 7);
    ga[i] = A + (size_t)(bm + r) * K + c * 8;
    oa[i] = lam * 8;
  }
#pragma unroll
  for (int i = 0; i < 2; ++i) {
    int lam = i * 256 + wid * 64 + lane;
    int r = lam >> 3, c = (lam & 7) ^ (r & 7);
    gb[i] = Bt + (size_t)(bn + r) * K + c * 8;
    ob[i] = lam * 8;
  }
#pragma unroll
  for (int i = 0; i < 4; ++i) { gl2lds16(ga[i], &Abuf[0][oa[i]]); ga[i] += 64; }
#pragma unroll
  for (int i = 0; i < 2; ++i) { gl2lds16(gb[i], &Bbuf[0][ob[i]]); gb[i] += 64; }

  f32x4 acc[2][4] = {};
  const int sw = li & 7;
  for (int s = 0; s < 8; ++s) {
    __builtin_amdgcn_s_barrier();          // A: all waves done reading buf (s+1)&1
    if (s + 1 < 8) {
      int p = (s + 1) & 1;
#pragma unroll
      for (int i = 0; i < 4; ++i) { gl2lds16(ga[i], &Abuf[p][oa[i]]); ga[i] += 64; }
#pragma unroll
      for (int i = 0; i < 2; ++i) { gl2lds16(gb[i], &Bbuf[p][ob[i]]); gb[i] += 64; }
      asm volatile("s_waitcnt vmcnt(6)" ::: "memory");   // drain s's loads only
    } else {
      asm volatile("s_waitcnt vmcnt(0)" ::: "memory");
    }
    __builtin_amdgcn_s_barrier();          // B: publish tile s
    __builtin_amdgcn_sched_barrier(0);
    const unsigned short* As = &Abuf[s & 1][0];
    const unsigned short* Bs = &Bbuf[s & 1][0];
#pragma unroll
    for (int kk = 0; kk < 2; ++kk) {
      bf16x8 af[2], bfr[4];
#pragma unroll
      for (int t = 0; t < 2; ++t)
        af[t] = *(const bf16x8*)(As + (wm + t * 16 + li) * 64 + (((kk * 4 + quad) ^ sw) * 8));
#pragma unroll
      for (int t = 0; t < 4; ++t)
        bfr[t] = *(const bf16x8*)(Bs + (t * 16 + li) * 64 + (((kk * 4 + quad) ^ sw) * 8));
#pragma unroll
      for (int mt = 0; mt < 2; ++mt)
#pragma unroll
        for (int nt = 0; nt < 4; ++nt)
          acc[mt][nt] = __builtin_amdgcn_mfma_f32_16x16x32_bf16(af[mt], bfr[nt], acc[mt][nt], 0, 0, 0);
    }
  }
#pragma unroll
  for (int mt = 0; mt < 2; ++mt)
#pragma unroll
    for (int nt = 0; nt < 4; ++nt) {
      int r0 = bm + wm + mt * 16 + quad * 4;
      int c  = bn + nt * 16 + li;
#pragma unroll
      for (int r = 0; r < 4; ++r)
        C[(size_t)(r0 + r) * LDC + c] = f2bf(acc[mt][nt][r] * scale);
    }
}

// ---- O-proj GEMM: out[8192][512] f32 = ob[8192][512] * WoT^T. Same structure. ----
__global__ __launch_bounds__(256) void gemm_o(const unsigned short* __restrict__ A,
                                              const unsigned short* __restrict__ Bt,
                                              float* __restrict__ Cf) {
  __shared__ __align__(16) unsigned short Abuf[2][128 * 64];
  __shared__ __align__(16) unsigned short Bbuf[2][64 * 64];
  const int K = 512, LDC = 512;
  const int tid = threadIdx.x;
  const int wid = tid >> 6, lane = tid & 63, quad = lane >> 4, li = lane & 15;
  const int bm = blockIdx.x * 128, bn = blockIdx.y * 64;
  const int wm = wid * 32;
  const unsigned short* ga[4]; int oa[4];
  const unsigned short* gb[2]; int ob[2];
#pragma unroll
  for (int i = 0; i < 4; ++i) {
    int lam = i * 256 + wid * 64 + lane;
    int r = lam >> 3, c = (lam & 7) ^ (r & 7);
    ga[i] = A + (size_t)(bm + r) * K + c * 8;
    oa[i] = lam * 8;
  }
#pragma unroll
  for (int i = 0; i < 2; ++i) {
    int lam = i * 256 + wid * 64 + lane;
    int r = lam >> 3, c = (lam & 7) ^ (r & 7);
    gb[i] = Bt + (size_t)(bn + r) * K + c * 8;
    ob[i] = lam * 8;
  }
#pragma unroll
  for (int i = 0; i < 4; ++i) { gl2lds16(ga[i], &Abuf[0][oa[i]]); ga[i] += 64; }
#pragma unroll
  for (int i = 0; i < 2; ++i) { gl2lds16(gb[i], &Bbuf[0][ob[i]]); gb[i] += 64; }

  f32x4 acc[2][4] = {};
  const int sw = li & 7;
  for (int s = 0; s < 8; ++s) {
    __builtin_amdgcn_s_barrier();
    if (s + 1 < 8) {
      int p = (s + 1) & 1;
#pragma unroll
      for (int i = 0; i < 4; ++i) { gl2lds16(ga[i], &Abuf[p][oa[i]]); ga[i] += 64; }
#pragma unroll
      for (int i = 0; i < 2; ++i) { gl2lds16(gb[i], &Bbuf[p][ob[i]]); gb[i] += 64; }
      asm volatile("s_waitcnt vmcnt(6)" ::: "memory");
    } else {
      asm volatile("s_waitcnt vmcnt(0)" ::: "memory");
    }
    __builtin_amdgcn_s_barrier();
    __builtin_amdgcn_sched_barrier(0);
    const unsigned short* As = &Abuf[s & 1][0];
    const unsigned short* Bs = &Bbuf[s & 1][0];
#pragma unroll
    for (int kk = 0; kk < 2; ++kk) {
      bf16x8 af[2], bfr[4];
#pragma unroll
      for (int t = 0; t < 2; ++t)
        af[t] = *(const bf16x8*)(As + (wm + t * 16 + li) * 64 + (((kk * 4 + quad) ^ sw) * 8));
#pragma unroll
      for (int t = 0; t < 4; ++t)
        bfr[t] = *(const bf16x8*)(Bs + (t * 16 + li) * 64 + (((kk * 4 + quad) ^ sw) * 8));
#pragma unroll
      for (int mt = 0; mt < 2; ++mt)
#pragma unroll
        for (int nt = 0; nt < 4; ++nt)
          acc[mt][nt] = __builtin_amdgcn_mfma_f32_16x16x32_bf16(af[mt], bfr[nt], acc[mt][nt], 0, 0, 0);
    }
  }
#pragma unroll
  for (int mt = 0; mt < 2; ++mt)
#pragma unroll
    for (int nt = 0; nt < 4; ++nt) {
      int r0 = bm + wm + mt * 16 + quad * 4;
      int c  = bn + nt * 16 + li;
#pragma unroll
      for (int r = 0; r < 4; ++r)
        Cf[(size_t)(r0 + r) * LDC + c] = acc[mt][nt][r];
    }
}

// ---- qkvh V-section -> vt [(b*8+h)*64+d][4096], with tau-permuted keys per 64-tile ----
// tau(p) = (p&32) | k<<4 | q<<2 | r   where p&31 = [q1 q0 k r1 r0]
// P.V is invariant under a shared key permutation; tau makes the S^T lane layout
// (keys kb*16+quad*4+r) directly usable as the PV A-fragment with NO P LDS round-trip.
__global__ __launch_bounds__(256) void vtrans(const unsigned short* __restrict__ qkv,
                                              unsigned short* __restrict__ vt) {
  __shared__ __align__(16) unsigned short T[64 * 72];
  const int kt = blockIdx.x;
  const int bh = blockIdx.y;
  const int b = bh >> 3, h = bh & 7;
  const int tid = threadIdx.x;
#pragma unroll
  for (int i = 0; i < 2; ++i) {
    int chunk = i * 256 + tid;
    int row = chunk >> 3, c8 = chunk & 7;
    *(uint4*)(T + row * 72 + c8 * 8) =
        *(const uint4*)(qkv + (size_t)(b * 4096 + kt * 64 + row) * 1536 + 1024 + h * 64 + c8 * 8);
  }
  __syncthreads();
#pragma unroll
  for (int i = 0; i < 2; ++i) {
    int chunk = i * 256 + tid;
    int dr = chunk >> 3, c8 = chunk & 7;
    u16x8 v;
#pragma unroll
    for (int j = 0; j < 8; ++j) {
      int p = c8 * 8 + j;
      int ph = p & 31;
      int lk = (p & 32) | (((ph >> 2) & 1) << 4) | (((ph >> 3) & 3) << 2) | (ph & 3);
      v[j] = T[lk * 72 + dr];
    }
    *(u16x8*)(vt + (size_t)(bh * 64 + dr) * 4096 + kt * 64 + c8 * 8) = v;
  }
}

// ---- flash attention v4: in-block split-KV (8 waves x 32q; waves 0-3 keys 0-2047,
// waves 4-7 keys 2048-4095; NO-MAX softmax partials additive, LDS combine).
// v4 changes vs v3: 2-step unrolled loop (ds addresses loop-invariant; parity ->
// +16384B immediate), kb-pair softmax (halved s[] live range -> no spill),
// v_cvt_pk_bf16_f32 packing (1 inst / 2 floats, was 3).
__global__ __launch_bounds__(512, 4) void attn(const unsigned short* __restrict__ qkv,
                                               const unsigned short* __restrict__ vt,
                                               const int* __restrict__ mask,
                                               unsigned short* __restrict__ obuf) {
  // SM layout (shorts): Kb [par][hv][4096] = 16384 | Vb same = 16384 | Msk 256
  __shared__ __align__(16) unsigned short SM[33024];
  unsigned short* Kb = SM;
  unsigned short* Vb = SM + 16384;
  unsigned short* Mk = SM + 32768;
  const int qt = blockIdx.x, h = blockIdx.y, b = blockIdx.z;
  const int tid = threadIdx.x;
  const int wid = tid >> 6, lane = tid & 63, quad = lane >> 4, li = lane & 15;
  const int hv = wid >> 2;   // which KV half this wave computes
  const int wq = wid & 3;    // query group of 32
  const size_t tok0 = (size_t)b * 4096;

  if (tid < 256) {
    const int4* mp = (const int4*)(mask + b * 4096 + tid * 16);
    unsigned int bits = 0;
#pragma unroll
    for (int j = 0; j < 4; ++j) {
      int4 m4 = mp[j];
      bits |= (m4.x ? 1u : 0u) << (j * 4 + 0);
      bits |= (m4.y ? 1u : 0u) << (j * 4 + 1);
      bits |= (m4.z ? 1u : 0u) << (j * 4 + 2);
      bits |= (m4.w ? 1u : 0u) << (j * 4 + 3);
    }
    Mk[tid] = (unsigned short)bits;
  }

  // Q as B-operand: wave owns queries qt*128 + wq*32 + qg*16 + li (qg = 0,1)
  const unsigned short* qp0 = qkv + (tok0 + qt * 128 + wq * 32 + li) * 1536 + h * 64;
  const unsigned short* qp1 = qp0 + (size_t)16 * 1536;
  bf16x8 bq[2][2];
  bq[0][0] = *(const bf16x8*)(qp0 + quad * 8);
  bq[0][1] = *(const bf16x8*)(qp0 + 32 + quad * 8);
  bq[1][0] = *(const bf16x8*)(qp1 + quad * 8);
  bq[1][1] = *(const bf16x8*)(qp1 + 32 + quad * 8);

  // staging: all 512 threads; each stages 1 chunk of each of {K0,K1,V0,V1} per step
  const unsigned short* kbase = qkv + tok0 * 1536 + 512 + h * 64;
  const unsigned short* vbase = vt + (size_t)(b * 8 + h) * 64 * 4096;
  const int sr = tid >> 3, sc8 = ((tid & 7) ^ (sr & 7)) * 8;
  const unsigned short* gk0 = kbase + (size_t)sr * 1536 + sc8;                  // half 0
  const unsigned short* gk1 = kbase + (size_t)(2048 + sr) * 1536 + sc8;         // half 1
  const unsigned short* gv0 = vbase + (size_t)sr * 4096 + sc8;                  // half 0
  const unsigned short* gv1 = vbase + (size_t)sr * 4096 + 2048 + sc8;           // half 1
  const int ol = tid * 8;   // short offset of this thread's chunk within a tile

  gl2lds16(gk0, Kb + ol);          gl2lds16(gk1, Kb + 4096 + ol);
  gl2lds16(gv0, Vb + ol);          gl2lds16(gv1, Vb + 4096 + ol);
  gk0 += (size_t)64 * 1536; gk1 += (size_t)64 * 1536; gv0 += 64; gv1 += 64;

  f32x4 lacc[2] = {};
  f32x4 accO[2][4] = {};
  const int sw = li & 7;
  const int xo0 = (quad ^ sw) * 8;
  const int xo1 = ((4 + quad) ^ sw) * 8;
  const unsigned short* Kw = Kb + hv * 4096;   // parity-0 K tile base for this wave
  const unsigned short* Vw = Vb + hv * 4096;

  // one step of work on tile at (Ks, Vs), global tile index tt
  auto STEP = [&](const unsigned short* Ks, const unsigned short* Vs, int tt) {
    unsigned long long mbits = *(const unsigned long long*)(Mk + tt * 4);
    bf16x8 pf[2][2];
#pragma unroll
    for (int kbp = 0; kbp < 2; ++kbp) {
      const unsigned short* kra = Ks + ((kbp * 2 + 0) * 16 + li) * 64;
      const unsigned short* krb = Ks + ((kbp * 2 + 1) * 16 + li) * 64;
      bf16x8 a0 = *(const bf16x8*)(kra + xo0);
      bf16x8 a1 = *(const bf16x8*)(kra + xo1);
      bf16x8 c0 = *(const bf16x8*)(krb + xo0);
      bf16x8 c1 = *(const bf16x8*)(krb + xo1);
      f32x4 s0[2], s1[2];
      __builtin_amdgcn_s_setprio(1);
#pragma unroll
      for (int qg = 0; qg < 2; ++qg) {
        f32x4 z = {};
        z = __builtin_amdgcn_mfma_f32_16x16x32_bf16(a0, bq[qg][0], z, 0, 0, 0);
        z = __builtin_amdgcn_mfma_f32_16x16x32_bf16(a1, bq[qg][1], z, 0, 0, 0);
        s0[qg] = z;
        f32x4 w = {};
        w = __builtin_amdgcn_mfma_f32_16x16x32_bf16(c0, bq[qg][0], w, 0, 0, 0);
        w = __builtin_amdgcn_mfma_f32_16x16x32_bf16(c1, bq[qg][1], w, 0, 0, 0);
        s1[qg] = w;
      }
      __builtin_amdgcn_s_setprio(0);
      if (mbits != ~0ull) {
#pragma unroll
        for (int r = 0; r < 4; ++r) {
          int k0 = (kbp * 2 + 0) * 16 + quad * 4 + r;
          int k1 = (kbp * 2 + 1) * 16 + quad * 4 + r;
          if (!((mbits >> k0) & 1ull)) { s0[0][r] = -1e30f; s0[1][r] = -1e30f; }
          if (!((mbits >> k1) & 1ull)) { s1[0][r] = -1e30f; s1[1][r] = -1e30f; }
        }
      }
#pragma unroll
      for (int qg = 0; qg < 2; ++qg) {
#pragma unroll
        for (int r = 0; r < 4; ++r) {
          s0[qg][r] = __builtin_amdgcn_exp2f(s0[qg][r]);
          s1[qg][r] = __builtin_amdgcn_exp2f(s1[qg][r]);
        }
        lacc[qg] += s0[qg];
        lacc[qg] += s1[qg];
        uint4 u;
        u.x = cvtpk(s0[qg][0], s0[qg][1]); u.y = cvtpk(s0[qg][2], s0[qg][3]);
        u.z = cvtpk(s1[qg][0], s1[qg][1]); u.w = cvtpk(s1[qg][2], s1[qg][3]);
        pf[qg][kbp] = __builtin_bit_cast(bf16x8, u);
      }
    }
    // O += P V ; V reads shared by both qg
    __builtin_amdgcn_s_setprio(1);
#pragma unroll
    for (int dc = 0; dc < 4; ++dc) {
      const unsigned short* vr = Vs + (dc * 16 + li) * 64;
      bf16x8 bv0 = *(const bf16x8*)(vr + xo0);
      bf16x8 bv1 = *(const bf16x8*)(vr + xo1);
#pragma unroll
      for (int qg = 0; qg < 2; ++qg) {
        accO[qg][dc] = __builtin_amdgcn_mfma_f32_16x16x32_bf16(pf[qg][0], bv0, accO[qg][dc], 0, 0, 0);
        accO[qg][dc] = __builtin_amdgcn_mfma_f32_16x16x32_bf16(pf[qg][1], bv1, accO[qg][dc], 0, 0, 0);
      }
    }
    __builtin_amdgcn_s_setprio(0);
  };

  // publish Mk before first raw barrier (raw s_barrier doesn't drain lgkm)
  asm volatile("s_waitcnt lgkmcnt(0)" ::: "memory");

  for (int i = 0; i < 16; ++i) {
    // ---- even sub-step t = 2i (parity 0 in use) ----
    __builtin_amdgcn_s_barrier();          // A: all waves done with parity-1 buf
    {
      gl2lds16(gk0, Kb + 8192 + ol);   gl2lds16(gk1, Kb + 8192 + 4096 + ol);
      gl2lds16(gv0, Vb + 8192 + ol);   gl2lds16(gv1, Vb + 8192 + 4096 + ol);
      gk0 += (size_t)64 * 1536; gk1 += (size_t)64 * 1536; gv0 += 64; gv1 += 64;
      asm volatile("s_waitcnt vmcnt(4)" ::: "memory");  // drain parity-0 loads only
    }
    __builtin_amdgcn_s_barrier();          // B: publish parity 0
    __builtin_amdgcn_sched_barrier(0);
    STEP(Kw, Vw, hv * 32 + 2 * i);

    // ---- odd sub-step t = 2i+1 (parity 1 in use) ----
    __builtin_amdgcn_s_barrier();          // A: all waves done with parity-0 buf
    if (i < 15) {
      gl2lds16(gk0, Kb + ol);          gl2lds16(gk1, Kb + 4096 + ol);
      gl2lds16(gv0, Vb + ol);          gl2lds16(gv1, Vb + 4096 + ol);
      gk0 += (size_t)64 * 1536; gk1 += (size_t)64 * 1536; gv0 += 64; gv1 += 64;
      asm volatile("s_waitcnt vmcnt(4)" ::: "memory");  // drain parity-1 loads only
    } else {
      asm volatile("s_waitcnt vmcnt(0)" ::: "memory");
    }
    __builtin_amdgcn_s_barrier();          // B: publish parity 1
    __builtin_amdgcn_sched_barrier(0);
    STEP(Kw + 8192, Vw + 8192, hv * 32 + 2 * i + 1);
  }

  // ---- combine halves: waves 4-7 dump partials to LDS; waves 0-3 add + store ----
  __syncthreads();                       // K/V buffers dead; reuse as f32 scratch (40 KB)
  float* scr = (float*)SM;               // layout: scr[j*256 + wq*64 + lane], j in 0..39
  if (hv == 1) {
#pragma unroll
    for (int qg = 0; qg < 2; ++qg) {
#pragma unroll
      for (int dc = 0; dc < 4; ++dc)
#pragma unroll
        for (int r = 0; r < 4; ++r)
          scr[(qg * 16 + dc * 4 + r) * 256 + wq * 64 + lane] = accO[qg][dc][r];
#pragma unroll
      for (int r = 0; r < 4; ++r)
        scr[(32 + qg * 4 + r) * 256 + wq * 64 + lane] = lacc[qg][r];
    }
  }
  __syncthreads();
  if (hv == 0) {
#pragma unroll
    for (int qg = 0; qg < 2; ++qg) {
#pragma unroll
      for (int dc = 0; dc < 4; ++dc)
#pragma unroll
        for (int r = 0; r < 4; ++r)
          accO[qg][dc][r] += scr[(qg * 16 + dc * 4 + r) * 256 + wq * 64 + lane];
#pragma unroll
      for (int r = 0; r < 4; ++r)
        lacc[qg][r] += scr[(32 + qg * 4 + r) * 256 + wq * 64 + lane];
    }
    // full l per query, then normalize + store
#pragma unroll
    for (int qg = 0; qg < 2; ++qg) {
      float lt = lacc[qg][0] + lacc[qg][1] + lacc[qg][2] + lacc[qg][3];
      lt += __shfl_xor(lt, 16);
      lt += __shfl_xor(lt, 32);
      float lv0 = 1.f / __shfl(lt, quad * 4 + 0);
      float lv1 = 1.f / __shfl(lt, quad * 4 + 1);
      float lv2 = 1.f / __shfl(lt, quad * 4 + 2);
      float lv3 = 1.f / __shfl(lt, quad * 4 + 3);
      size_t r0q = tok0 + qt * 128 + wq * 32 + qg * 16 + quad * 4;
#pragma unroll
      for (int dc = 0; dc < 4; ++dc) {
        size_t col = h * 64 + dc * 16 + li;
        obuf[(r0q + 0) * 512 + col] = f2bf(accO[qg][dc][0] * lv0);
        obuf[(r0q + 1) * 512 + col] = f2bf(accO[qg][dc][1] * lv1);
        obuf[(r0q + 2) * 512 + col] = f2bf(accO[qg][dc][2] * lv2);
        obuf[(r0q + 3) * 512 + col] = f2bf(accO[qg][dc][3] * lv3);
      }
    }
  }
}

extern "C" void kernel_launch(void* const* d_in, const int* in_sizes, int n_in,
                              void* d_out, int out_size, void* d_ws, size_t ws_size,
                              hipStream_t stream) {
  const float* q  = (const float*)d_in[0];
  const float* k  = (const float*)d_in[1];
  const float* v  = (const float*)d_in[2];
  const int* mask = (const int*)d_in[3];
  const float* Wq = (const float*)d_in[4];
  const float* Wk = (const float*)d_in[5];
  const float* Wv = (const float*)d_in[6];
  const float* Wo = (const float*)d_in[7];
  float* out = (float*)d_out;

  char* ws = (char*)d_ws;
  const size_t SA = (size_t)8192 * 512 * 2;   // 8 MB
  unsigned short* qbf  = (unsigned short*)(ws);
  unsigned short* kbf  = (unsigned short*)(ws + SA);
  unsigned short* vbf  = (unsigned short*)(ws + 2 * SA);
  unsigned short* qkvh = (unsigned short*)(ws + 3 * SA);          // 24 MB
  unsigned short* wAll = (unsigned short*)(ws + 6 * SA);          // 2 MB
  unsigned short* woT  = wAll + (size_t)3 * 512 * 512;
  unsigned short* vtb  = qbf;  // dead after gemm_qkv
  unsigned short* ob   = kbf;  // dead after gemm_qkv

  dim3 cg(2048, 3);
  cvt3<<<cg, 256, 0, stream>>>(q, k, v, qbf, kbf, vbf);
  dim3 wg(8, 8, 4);
  wtrans4<<<wg, 256, 0, stream>>>(Wq, Wk, Wv, Wo, wAll);
  const float qscale = 0.125f * 1.44269504f;  // 1/sqrt(64) * log2(e)
  dim3 gq(64, 24);
  gemm_qkv<<<gq, 256, 0, stream>>>(qbf, kbf, vbf, wAll, qkvh, qscale);
  dim3 vg(64, 16);
  vtrans<<<vg, 256, 0, stream>>>(qkvh, vtb);
  dim3 ag(32, 8, 2);
  attn<<<ag, 512, 0, stream>>>(qkvh, vtb, mask, ob);
  dim3 go(64, 8);
  gemm_o<<<go, 256, 0, stream>>>(ob, woT, out);
}

// Round 5
// 222.112 us; speedup vs baseline: 1.4206x; 1.4206x over previous
//
#include <hip/hip_runtime.h>

typedef short bf16x8 __attribute__((ext_vector_type(8)));
typedef float f32x4 __attribute__((ext_vector_type(4)));
typedef unsigned short u16x8 __attribute__((ext_vector_type(8)));

static __device__ __forceinline__ unsigned short f2bf(float f) {
  unsigned int x = __builtin_bit_cast(unsigned int, f);
  x += 0x7FFFu + ((x >> 16) & 1u);   // RNE
  return (unsigned short)(x >> 16);
}
// pack two floats' bf16 (round-half-up) into one u32 (lo=a, hi=b)
static __device__ __forceinline__ unsigned int pk2bf(float a, float b) {
  unsigned int ia = __builtin_bit_cast(unsigned int, a) + 0x8000u;
  unsigned int ib = __builtin_bit_cast(unsigned int, b) + 0x8000u;
  return __builtin_amdgcn_perm(ib, ia, 0x07060302u);
}
// HW packed f32->bf16 (RNE), 1 instruction for 2 values: lo=a, hi=b
static __device__ __forceinline__ unsigned int cvtpk(float a, float b) {
  unsigned int r;
  asm("v_cvt_pk_bf16_f32 %0, %1, %2" : "=v"(r) : "v"(a), "v"(b));
  return r;
}
// async 16B global -> LDS
static __device__ __forceinline__ void gl2lds16(const unsigned short* g, unsigned short* l) {
  __builtin_amdgcn_global_load_lds(
      (const __attribute__((address_space(1))) unsigned int*)g,
      (__attribute__((address_space(3))) unsigned int*)l, 16, 0, 0);
}

// ---------------- fused q/k/v fp32 -> bf16 (8 elems/thread) ----------------
__global__ __launch_bounds__(256) void cvt3(const float* __restrict__ q, const float* __restrict__ k,
                                            const float* __restrict__ v,
                                            unsigned short* __restrict__ qo, unsigned short* __restrict__ ko,
                                            unsigned short* __restrict__ vo) {
  const float* src = (blockIdx.y == 0) ? q : (blockIdx.y == 1) ? k : v;
  unsigned short* dst = (blockIdx.y == 0) ? qo : (blockIdx.y == 1) ? ko : vo;
  int i = (blockIdx.x * 256 + threadIdx.x) * 8;
  float4 a = *(const float4*)(src + i);
  float4 b = *(const float4*)(src + i + 4);
  uint4 pk;
  pk.x = pk2bf(a.x, a.y); pk.y = pk2bf(a.z, a.w);
  pk.z = pk2bf(b.x, b.y); pk.w = pk2bf(b.z, b.w);
  *(uint4*)(dst + i) = pk;
}

// ------- 4x W [512k][512n] f32 -> WT [4][512n][512k] bf16 (z selects matrix) -------
__global__ __launch_bounds__(256) void wtrans4(const float* __restrict__ Wq, const float* __restrict__ Wk,
                                               const float* __restrict__ Wv, const float* __restrict__ Wo,
                                               unsigned short* __restrict__ WT) {
  __shared__ __align__(16) float T[64 * 68];
  const int z = blockIdx.z;
  const float* W = (z == 0) ? Wq : (z == 1) ? Wk : (z == 2) ? Wv : Wo;
  unsigned short* out = WT + (size_t)z * 512 * 512;
  const int k0 = blockIdx.x * 64, n0 = blockIdx.y * 64;
  const int tid = threadIdx.x;
#pragma unroll
  for (int i = 0; i < 4; ++i) {
    int chunk = i * 256 + tid;
    int row = chunk >> 4, fc = chunk & 15;
    *(float4*)(T + row * 68 + fc * 4) =
        *(const float4*)(W + (size_t)(k0 + row) * 512 + n0 + fc * 4);
  }
  __syncthreads();
#pragma unroll
  for (int i = 0; i < 2; ++i) {
    int chunk = i * 256 + tid;
    int nr = chunk >> 3, kc = chunk & 7;
    u16x8 v;
#pragma unroll
    for (int j = 0; j < 8; ++j) v[j] = f2bf(T[(kc * 8 + j) * 68 + nr]);
    *(u16x8*)(out + (size_t)(n0 + nr) * 512 + k0 + kc * 8) = v;
  }
}

// ---- fused QKV GEMM: C[8192][1536] = [q|k|v] proj. 128x64 tile, BK=64, async dbuf. ----
__global__ __launch_bounds__(256) void gemm_qkv(const unsigned short* __restrict__ Aq,
                                                const unsigned short* __restrict__ Ak,
                                                const unsigned short* __restrict__ Av,
                                                const unsigned short* __restrict__ Bt,
                                                unsigned short* __restrict__ C,
                                                float qscale) {
  __shared__ __align__(16) unsigned short Abuf[2][128 * 64];
  __shared__ __align__(16) unsigned short Bbuf[2][64 * 64];
  const int K = 512, LDC = 1536;
  const unsigned short* A = (blockIdx.y < 8) ? Aq : (blockIdx.y < 16) ? Ak : Av;
  const float scale = (blockIdx.y < 8) ? qscale : 1.0f;
  const int tid = threadIdx.x;
  const int wid = tid >> 6, lane = tid & 63, quad = lane >> 4, li = lane & 15;
  const int bm = blockIdx.x * 128, bn = blockIdx.y * 64;
  const int wm = wid * 32;
  const unsigned short* ga[4]; int oa[4];
  const unsigned short* gb[2]; int ob[2];
#pragma unroll
  for (int i = 0; i < 4; ++i) {
    int lam = i * 256 + wid * 64 + lane;
    int r = lam >> 3, c = (lam & 7) ^ (r & 7);
    ga[i] = A + (size_t)(bm + r) * K + c * 8;
    oa[i] = lam * 8;
  }
#pragma unroll
  for (int i = 0; i < 2; ++i) {
    int lam = i * 256 + wid * 64 + lane;
    int r = lam >> 3, c = (lam & 7) ^ (r & 7);
    gb[i] = Bt + (size_t)(bn + r) * K + c * 8;
    ob[i] = lam * 8;
  }
#pragma unroll
  for (int i = 0; i < 4; ++i) { gl2lds16(ga[i], &Abuf[0][oa[i]]); ga[i] += 64; }
#pragma unroll
  for (int i = 0; i < 2; ++i) { gl2lds16(gb[i], &Bbuf[0][ob[i]]); gb[i] += 64; }

  f32x4 acc[2][4] = {};
  const int sw = li & 7;
  for (int s = 0; s < 8; ++s) {
    __builtin_amdgcn_s_barrier();          // A: all waves done reading buf (s+1)&1
    if (s + 1 < 8) {
      int p = (s + 1) & 1;
#pragma unroll
      for (int i = 0; i < 4; ++i) { gl2lds16(ga[i], &Abuf[p][oa[i]]); ga[i] += 64; }
#pragma unroll
      for (int i = 0; i < 2; ++i) { gl2lds16(gb[i], &Bbuf[p][ob[i]]); gb[i] += 64; }
      asm volatile("s_waitcnt vmcnt(6)" ::: "memory");   // drain s's loads only
    } else {
      asm volatile("s_waitcnt vmcnt(0)" ::: "memory");
    }
    __builtin_amdgcn_s_barrier();          // B: publish tile s
    __builtin_amdgcn_sched_barrier(0);
    const unsigned short* As = &Abuf[s & 1][0];
    const unsigned short* Bs = &Bbuf[s & 1][0];
#pragma unroll
    for (int kk = 0; kk < 2; ++kk) {
      bf16x8 af[2], bfr[4];
#pragma unroll
      for (int t = 0; t < 2; ++t)
        af[t] = *(const bf16x8*)(As + (wm + t * 16 + li) * 64 + (((kk * 4 + quad) ^ sw) * 8));
#pragma unroll
      for (int t = 0; t < 4; ++t)
        bfr[t] = *(const bf16x8*)(Bs + (t * 16 + li) * 64 + (((kk * 4 + quad) ^ sw) * 8));
#pragma unroll
      for (int mt = 0; mt < 2; ++mt)
#pragma unroll
        for (int nt = 0; nt < 4; ++nt)
          acc[mt][nt] = __builtin_amdgcn_mfma_f32_16x16x32_bf16(af[mt], bfr[nt], acc[mt][nt], 0, 0, 0);
    }
  }
#pragma unroll
  for (int mt = 0; mt < 2; ++mt)
#pragma unroll
    for (int nt = 0; nt < 4; ++nt) {
      int r0 = bm + wm + mt * 16 + quad * 4;
      int c  = bn + nt * 16 + li;
#pragma unroll
      for (int r = 0; r < 4; ++r)
        C[(size_t)(r0 + r) * LDC + c] = f2bf(acc[mt][nt][r] * scale);
    }
}

// ---- O-proj GEMM: out[8192][512] f32 = ob[8192][512] * WoT^T. Same structure. ----
__global__ __launch_bounds__(256) void gemm_o(const unsigned short* __restrict__ A,
                                              const unsigned short* __restrict__ Bt,
                                              float* __restrict__ Cf) {
  __shared__ __align__(16) unsigned short Abuf[2][128 * 64];
  __shared__ __align__(16) unsigned short Bbuf[2][64 * 64];
  const int K = 512, LDC = 512;
  const int tid = threadIdx.x;
  const int wid = tid >> 6, lane = tid & 63, quad = lane >> 4, li = lane & 15;
  const int bm = blockIdx.x * 128, bn = blockIdx.y * 64;
  const int wm = wid * 32;
  const unsigned short* ga[4]; int oa[4];
  const unsigned short* gb[2]; int ob[2];
#pragma unroll
  for (int i = 0; i < 4; ++i) {
    int lam = i * 256 + wid * 64 + lane;
    int r = lam >> 3, c = (lam & 7) ^ (r & 7);
    ga[i] = A + (size_t)(bm + r) * K + c * 8;
    oa[i] = lam * 8;
  }
#pragma unroll
  for (int i = 0; i < 2; ++i) {
    int lam = i * 256 + wid * 64 + lane;
    int r = lam >> 3, c = (lam & 7) ^ (r & 7);
    gb[i] = Bt + (size_t)(bn + r) * K + c * 8;
    ob[i] = lam * 8;
  }
#pragma unroll
  for (int i = 0; i < 4; ++i) { gl2lds16(ga[i], &Abuf[0][oa[i]]); ga[i] += 64; }
#pragma unroll
  for (int i = 0; i < 2; ++i) { gl2lds16(gb[i], &Bbuf[0][ob[i]]); gb[i] += 64; }

  f32x4 acc[2][4] = {};
  const int sw = li & 7;
  for (int s = 0; s < 8; ++s) {
    __builtin_amdgcn_s_barrier();
    if (s + 1 < 8) {
      int p = (s + 1) & 1;
#pragma unroll
      for (int i = 0; i < 4; ++i) { gl2lds16(ga[i], &Abuf[p][oa[i]]); ga[i] += 64; }
#pragma unroll
      for (int i = 0; i < 2; ++i) { gl2lds16(gb[i], &Bbuf[p][ob[i]]); gb[i] += 64; }
      asm volatile("s_waitcnt vmcnt(6)" ::: "memory");
    } else {
      asm volatile("s_waitcnt vmcnt(0)" ::: "memory");
    }
    __builtin_amdgcn_s_barrier();
    __builtin_amdgcn_sched_barrier(0);
    const unsigned short* As = &Abuf[s & 1][0];
    const unsigned short* Bs = &Bbuf[s & 1][0];
#pragma unroll
    for (int kk = 0; kk < 2; ++kk) {
      bf16x8 af[2], bfr[4];
#pragma unroll
      for (int t = 0; t < 2; ++t)
        af[t] = *(const bf16x8*)(As + (wm + t * 16 + li) * 64 + (((kk * 4 + quad) ^ sw) * 8));
#pragma unroll
      for (int t = 0; t < 4; ++t)
        bfr[t] = *(const bf16x8*)(Bs + (t * 16 + li) * 64 + (((kk * 4 + quad) ^ sw) * 8));
#pragma unroll
      for (int mt = 0; mt < 2; ++mt)
#pragma unroll
        for (int nt = 0; nt < 4; ++nt)
          acc[mt][nt] = __builtin_amdgcn_mfma_f32_16x16x32_bf16(af[mt], bfr[nt], acc[mt][nt], 0, 0, 0);
    }
  }
#pragma unroll
  for (int mt = 0; mt < 2; ++mt)
#pragma unroll
    for (int nt = 0; nt < 4; ++nt) {
      int r0 = bm + wm + mt * 16 + quad * 4;
      int c  = bn + nt * 16 + li;
#pragma unroll
      for (int r = 0; r < 4; ++r)
        Cf[(size_t)(r0 + r) * LDC + c] = acc[mt][nt][r];
    }
}

// ---- qkvh V-section -> vt [(b*8+h)*64+d][4096], with tau-permuted keys per 64-tile ----
// tau(p) = (p&32) | k<<4 | q<<2 | r   where p&31 = [q1 q0 k r1 r0]
// P.V is invariant under a shared key permutation; tau makes the S^T lane layout
// (keys kb*16+quad*4+r) directly usable as the PV A-fragment with NO P LDS round-trip.
__global__ __launch_bounds__(256) void vtrans(const unsigned short* __restrict__ qkv,
                                              unsigned short* __restrict__ vt) {
  __shared__ __align__(16) unsigned short T[64 * 72];
  const int kt = blockIdx.x;
  const int bh = blockIdx.y;
  const int b = bh >> 3, h = bh & 7;
  const int tid = threadIdx.x;
#pragma unroll
  for (int i = 0; i < 2; ++i) {
    int chunk = i * 256 + tid;
    int row = chunk >> 3, c8 = chunk & 7;
    *(uint4*)(T + row * 72 + c8 * 8) =
        *(const uint4*)(qkv + (size_t)(b * 4096 + kt * 64 + row) * 1536 + 1024 + h * 64 + c8 * 8);
  }
  __syncthreads();
#pragma unroll
  for (int i = 0; i < 2; ++i) {
    int chunk = i * 256 + tid;
    int dr = chunk >> 3, c8 = chunk & 7;
    u16x8 v;
#pragma unroll
    for (int j = 0; j < 8; ++j) {
      int p = c8 * 8 + j;
      int ph = p & 31;
      int lk = (p & 32) | (((ph >> 2) & 1) << 4) | (((ph >> 3) & 3) << 2) | (ph & 3);
      v[j] = T[lk * 72 + dr];
    }
    *(u16x8*)(vt + (size_t)(bh * 64 + dr) * 4096 + kt * 64 + c8 * 8) = v;
  }
}

// ---- flash attention v5: R3 structure (in-block split-KV, 8 waves x 32q, NO-MAX
// softmax, LDS combine, in-register P via tau-permuted V), with the VGPR cap fixed:
// launch_bounds (512,2) so the compiler is NOT forced to 64 VGPRs (R3/R4 spilled).
// LDS (66 KB) limits to 2 blocks/CU = 16 waves/CU regardless; ~110 VGPR fits that.
__global__ __launch_bounds__(512, 2) void attn(const unsigned short* __restrict__ qkv,
                                               const unsigned short* __restrict__ vt,
                                               const int* __restrict__ mask,
                                               unsigned short* __restrict__ obuf) {
  // SM layout (shorts): Kb [par][hv][4096] = 16384 | Vb same = 16384 | Msk 256
  __shared__ __align__(16) unsigned short SM[33024];
  unsigned short* Kb = SM;
  unsigned short* Vb = SM + 16384;
  unsigned short* Mk = SM + 32768;
  const int qt = blockIdx.x, h = blockIdx.y, b = blockIdx.z;
  const int tid = threadIdx.x;
  const int wid = tid >> 6, lane = tid & 63, quad = lane >> 4, li = lane & 15;
  const int hv = wid >> 2;   // which KV half this wave computes
  const int wq = wid & 3;    // query group of 32
  const size_t tok0 = (size_t)b * 4096;

  if (tid < 256) {
    const int4* mp = (const int4*)(mask + b * 4096 + tid * 16);
    unsigned int bits = 0;
#pragma unroll
    for (int j = 0; j < 4; ++j) {
      int4 m4 = mp[j];
      bits |= (m4.x ? 1u : 0u) << (j * 4 + 0);
      bits |= (m4.y ? 1u : 0u) << (j * 4 + 1);
      bits |= (m4.z ? 1u : 0u) << (j * 4 + 2);
      bits |= (m4.w ? 1u : 0u) << (j * 4 + 3);
    }
    Mk[tid] = (unsigned short)bits;
  }

  // Q as B-operand: wave owns queries qt*128 + wq*32 + qg*16 + li (qg = 0,1)
  const unsigned short* qp0 = qkv + (tok0 + qt * 128 + wq * 32 + li) * 1536 + h * 64;
  const unsigned short* qp1 = qp0 + (size_t)16 * 1536;
  bf16x8 bq[2][2];
  bq[0][0] = *(const bf16x8*)(qp0 + quad * 8);
  bq[0][1] = *(const bf16x8*)(qp0 + 32 + quad * 8);
  bq[1][0] = *(const bf16x8*)(qp1 + quad * 8);
  bq[1][1] = *(const bf16x8*)(qp1 + 32 + quad * 8);

  // staging: all 512 threads; each stages 1 chunk of each of {K0,K1,V0,V1} per step
  const unsigned short* kbase = qkv + tok0 * 1536 + 512 + h * 64;
  const unsigned short* vbase = vt + (size_t)(b * 8 + h) * 64 * 4096;
  const int sr = tid >> 3, sc8 = ((tid & 7) ^ (sr & 7)) * 8;
  const unsigned short* gk0 = kbase + (size_t)sr * 1536 + sc8;                  // half 0
  const unsigned short* gk1 = kbase + (size_t)(2048 + sr) * 1536 + sc8;         // half 1
  const unsigned short* gv0 = vbase + (size_t)sr * 4096 + sc8;                  // half 0
  const unsigned short* gv1 = vbase + (size_t)sr * 4096 + 2048 + sc8;           // half 1
  const int ol = tid * 8;   // short offset of this thread's chunk within a tile

  gl2lds16(gk0, Kb + ol);          gl2lds16(gk1, Kb + 4096 + ol);
  gl2lds16(gv0, Vb + ol);          gl2lds16(gv1, Vb + 4096 + ol);
  gk0 += (size_t)64 * 1536; gk1 += (size_t)64 * 1536; gv0 += 64; gv1 += 64;

  f32x4 lacc[2] = {};
  f32x4 accO[2][4] = {};
  const int sw = li & 7;

  // publish Mk before first raw barrier (raw s_barrier doesn't drain lgkm)
  asm volatile("s_waitcnt lgkmcnt(0)" ::: "memory");

  for (int t = 0; t < 32; ++t) {
    __builtin_amdgcn_s_barrier();          // A: all waves done with buf (t+1)&1
    if (t < 31) {
      int p = (t + 1) & 1;
      unsigned short* kd = Kb + p * 8192;
      unsigned short* vd = Vb + p * 8192;
      gl2lds16(gk0, kd + ol);        gl2lds16(gk1, kd + 4096 + ol);
      gl2lds16(gv0, vd + ol);        gl2lds16(gv1, vd + 4096 + ol);
      gk0 += (size_t)64 * 1536; gk1 += (size_t)64 * 1536; gv0 += 64; gv1 += 64;
      asm volatile("s_waitcnt vmcnt(4)" ::: "memory");  // drain step t's loads only
    } else {
      asm volatile("s_waitcnt vmcnt(0)" ::: "memory");
    }
    __builtin_amdgcn_s_barrier();          // B: publish step t
    __builtin_amdgcn_sched_barrier(0);
    const unsigned short* Ks = Kb + (t & 1) * 8192 + hv * 4096;
    const unsigned short* Vs = Vb + (t & 1) * 8192 + hv * 4096;

    // S^T = K Q^T: lane = query li; keys kb*16 + quad*4 + r; K reads shared by both qg
    f32x4 s[2][4];
    __builtin_amdgcn_s_setprio(1);
#pragma unroll
    for (int kb = 0; kb < 4; ++kb) {
      const unsigned short* kr = Ks + (kb * 16 + li) * 64;
      bf16x8 ak0 = *(const bf16x8*)(kr + ((quad ^ sw) * 8));
      bf16x8 ak1 = *(const bf16x8*)(kr + (((4 + quad) ^ sw) * 8));
#pragma unroll
      for (int qg = 0; qg < 2; ++qg) {
        f32x4 z = {};
        z = __builtin_amdgcn_mfma_f32_16x16x32_bf16(ak0, bq[qg][0], z, 0, 0, 0);
        z = __builtin_amdgcn_mfma_f32_16x16x32_bf16(ak1, bq[qg][1], z, 0, 0, 0);
        s[qg][kb] = z;
      }
    }
    __builtin_amdgcn_s_setprio(0);
    int tt = hv * 32 + t;
    unsigned long long mbits = *(const unsigned long long*)(Mk + tt * 4);
    if (mbits != ~0ull) {
#pragma unroll
      for (int kb = 0; kb < 4; ++kb)
#pragma unroll
        for (int r = 0; r < 4; ++r) {
          int key = kb * 16 + quad * 4 + r;
          if (!((mbits >> key) & 1ull)) { s[0][kb][r] = -1e30f; s[1][kb][r] = -1e30f; }
        }
    }
    // p = exp2(s); partial l; pack in-register into PV A-fragments (tau-aligned)
    bf16x8 pf[2][2];
#pragma unroll
    for (int qg = 0; qg < 2; ++qg) {
#pragma unroll
      for (int kb = 0; kb < 4; ++kb) {
#pragma unroll
        for (int r = 0; r < 4; ++r) s[qg][kb][r] = __builtin_amdgcn_exp2f(s[qg][kb][r]);
        lacc[qg] += s[qg][kb];
      }
      uint4 u0, u1;
      u0.x = cvtpk(s[qg][0][0], s[qg][0][1]); u0.y = cvtpk(s[qg][0][2], s[qg][0][3]);
      u0.z = cvtpk(s[qg][1][0], s[qg][1][1]); u0.w = cvtpk(s[qg][1][2], s[qg][1][3]);
      u1.x = cvtpk(s[qg][2][0], s[qg][2][1]); u1.y = cvtpk(s[qg][2][2], s[qg][2][3]);
      u1.z = cvtpk(s[qg][3][0], s[qg][3][1]); u1.w = cvtpk(s[qg][3][2], s[qg][3][3]);
      pf[qg][0] = __builtin_bit_cast(bf16x8, u0);
      pf[qg][1] = __builtin_bit_cast(bf16x8, u1);
    }
    // O += P V ; V reads shared by both qg
    __builtin_amdgcn_s_setprio(1);
#pragma unroll
    for (int dc = 0; dc < 4; ++dc) {
      const unsigned short* vr = Vs + (dc * 16 + li) * 64;
      bf16x8 bv0 = *(const bf16x8*)(vr + ((quad ^ sw) * 8));
      bf16x8 bv1 = *(const bf16x8*)(vr + (((4 + quad) ^ sw) * 8));
#pragma unroll
      for (int qg = 0; qg < 2; ++qg) {
        accO[qg][dc] = __builtin_amdgcn_mfma_f32_16x16x32_bf16(pf[qg][0], bv0, accO[qg][dc], 0, 0, 0);
        accO[qg][dc] = __builtin_amdgcn_mfma_f32_16x16x32_bf16(pf[qg][1], bv1, accO[qg][dc], 0, 0, 0);
      }
    }
    __builtin_amdgcn_s_setprio(0);
  }

  // ---- combine halves: waves 4-7 dump partials to LDS; waves 0-3 add + store ----
  __syncthreads();                       // K/V buffers dead; reuse as f32 scratch (40 KB)
  float* scr = (float*)SM;               // layout: scr[j*256 + wq*64 + lane], j in 0..39
  if (hv == 1) {
#pragma unroll
    for (int qg = 0; qg < 2; ++qg) {
#pragma unroll
      for (int dc = 0; dc < 4; ++dc)
#pragma unroll
        for (int r = 0; r < 4; ++r)
          scr[(qg * 16 + dc * 4 + r) * 256 + wq * 64 + lane] = accO[qg][dc][r];
#pragma unroll
      for (int r = 0; r < 4; ++r)
        scr[(32 + qg * 4 + r) * 256 + wq * 64 + lane] = lacc[qg][r];
    }
  }
  __syncthreads();
  if (hv == 0) {
#pragma unroll
    for (int qg = 0; qg < 2; ++qg) {
#pragma unroll
      for (int dc = 0; dc < 4; ++dc)
#pragma unroll
        for (int r = 0; r < 4; ++r)
          accO[qg][dc][r] += scr[(qg * 16 + dc * 4 + r) * 256 + wq * 64 + lane];
#pragma unroll
      for (int r = 0; r < 4; ++r)
        lacc[qg][r] += scr[(32 + qg * 4 + r) * 256 + wq * 64 + lane];
    }
    // full l per query, then normalize + store
#pragma unroll
    for (int qg = 0; qg < 2; ++qg) {
      float lt = lacc[qg][0] + lacc[qg][1] + lacc[qg][2] + lacc[qg][3];
      lt += __shfl_xor(lt, 16);
      lt += __shfl_xor(lt, 32);
      float lv0 = 1.f / __shfl(lt, quad * 4 + 0);
      float lv1 = 1.f / __shfl(lt, quad * 4 + 1);
      float lv2 = 1.f / __shfl(lt, quad * 4 + 2);
      float lv3 = 1.f / __shfl(lt, quad * 4 + 3);
      size_t r0q = tok0 + qt * 128 + wq * 32 + qg * 16 + quad * 4;
#pragma unroll
      for (int dc = 0; dc < 4; ++dc) {
        size_t col = h * 64 + dc * 16 + li;
        obuf[(r0q + 0) * 512 + col] = f2bf(accO[qg][dc][0] * lv0);
        obuf[(r0q + 1) * 512 + col] = f2bf(accO[qg][dc][1] * lv1);
        obuf[(r0q + 2) * 512 + col] = f2bf(accO[qg][dc][2] * lv2);
        obuf[(r0q + 3) * 512 + col] = f2bf(accO[qg][dc][3] * lv3);
      }
    }
  }
}

extern "C" void kernel_launch(void* const* d_in, const int* in_sizes, int n_in,
                              void* d_out, int out_size, void* d_ws, size_t ws_size,
                              hipStream_t stream) {
  const float* q  = (const float*)d_in[0];
  const float* k  = (const float*)d_in[1];
  const float* v  = (const float*)d_in[2];
  const int* mask = (const int*)d_in[3];
  const float* Wq = (const float*)d_in[4];
  const float* Wk = (const float*)d_in[5];
  const float* Wv = (const float*)d_in[6];
  const float* Wo = (const float*)d_in[7];
  float* out = (float*)d_out;

  char* ws = (char*)d_ws;
  const size_t SA = (size_t)8192 * 512 * 2;   // 8 MB
  unsigned short* qbf  = (unsigned short*)(ws);
  unsigned short* kbf  = (unsigned short*)(ws + SA);
  unsigned short* vbf  = (unsigned short*)(ws + 2 * SA);
  unsigned short* qkvh = (unsigned short*)(ws + 3 * SA);          // 24 MB
  unsigned short* wAll = (unsigned short*)(ws + 6 * SA);          // 2 MB
  unsigned short* woT  = wAll + (size_t)3 * 512 * 512;
  unsigned short* vtb  = qbf;  // dead after gemm_qkv
  unsigned short* ob   = kbf;  // dead after gemm_qkv

  dim3 cg(2048, 3);
  cvt3<<<cg, 256, 0, stream>>>(q, k, v, qbf, kbf, vbf);
  dim3 wg(8, 8, 4);
  wtrans4<<<wg, 256, 0, stream>>>(Wq, Wk, Wv, Wo, wAll);
  const float qscale = 0.125f * 1.44269504f;  // 1/sqrt(64) * log2(e)
  dim3 gq(64, 24);
  gemm_qkv<<<gq, 256, 0, stream>>>(qbf, kbf, vbf, wAll, qkvh, qscale);
  dim3 vg(64, 16);
  vtrans<<<vg, 256, 0, stream>>>(qkvh, vtb);
  dim3 ag(32, 8, 2);
  attn<<<ag, 512, 0, stream>>>(qkvh, vtb, mask, ob);
  dim3 go(64, 8);
  gemm_o<<<go, 256, 0, stream>>>(ob, woT, out);
}

// Round 6
// 216.854 us; speedup vs baseline: 1.4550x; 1.0242x over previous
//
#include <hip/hip_runtime.h>

typedef short bf16x8 __attribute__((ext_vector_type(8)));
typedef float f32x4 __attribute__((ext_vector_type(4)));
typedef unsigned short u16x8 __attribute__((ext_vector_type(8)));

static __device__ __forceinline__ unsigned short f2bf(float f) {
  unsigned int x = __builtin_bit_cast(unsigned int, f);
  x += 0x7FFFu + ((x >> 16) & 1u);   // RNE
  return (unsigned short)(x >> 16);
}
// pack two floats' bf16 (round-half-up) into one u32 (lo=a, hi=b)
static __device__ __forceinline__ unsigned int pk2bf(float a, float b) {
  unsigned int ia = __builtin_bit_cast(unsigned int, a) + 0x8000u;
  unsigned int ib = __builtin_bit_cast(unsigned int, b) + 0x8000u;
  return __builtin_amdgcn_perm(ib, ia, 0x07060302u);
}
// HW packed f32->bf16 (RNE), 1 instruction for 2 values: lo=a, hi=b
static __device__ __forceinline__ unsigned int cvtpk(float a, float b) {
  unsigned int r;
  asm("v_cvt_pk_bf16_f32 %0, %1, %2" : "=v"(r) : "v"(a), "v"(b));
  return r;
}
// async 16B global -> LDS
static __device__ __forceinline__ void gl2lds16(const unsigned short* g, unsigned short* l) {
  __builtin_amdgcn_global_load_lds(
      (const __attribute__((address_space(1))) unsigned int*)g,
      (__attribute__((address_space(3))) unsigned int*)l, 16, 0, 0);
}

// ---------------- fused q/k/v fp32 -> bf16 (8 elems/thread) ----------------
__global__ __launch_bounds__(256) void cvt3(const float* __restrict__ q, const float* __restrict__ k,
                                            const float* __restrict__ v,
                                            unsigned short* __restrict__ qo, unsigned short* __restrict__ ko,
                                            unsigned short* __restrict__ vo) {
  const float* src = (blockIdx.y == 0) ? q : (blockIdx.y == 1) ? k : v;
  unsigned short* dst = (blockIdx.y == 0) ? qo : (blockIdx.y == 1) ? ko : vo;
  int i = (blockIdx.x * 256 + threadIdx.x) * 8;
  float4 a = *(const float4*)(src + i);
  float4 b = *(const float4*)(src + i + 4);
  uint4 pk;
  pk.x = pk2bf(a.x, a.y); pk.y = pk2bf(a.z, a.w);
  pk.z = pk2bf(b.x, b.y); pk.w = pk2bf(b.z, b.w);
  *(uint4*)(dst + i) = pk;
}

// ------- 4x W [512k][512n] f32 -> WT [4][512n][512k] bf16 (z selects matrix) -------
__global__ __launch_bounds__(256) void wtrans4(const float* __restrict__ Wq, const float* __restrict__ Wk,
                                               const float* __restrict__ Wv, const float* __restrict__ Wo,
                                               unsigned short* __restrict__ WT) {
  __shared__ __align__(16) float T[64 * 68];
  const int z = blockIdx.z;
  const float* W = (z == 0) ? Wq : (z == 1) ? Wk : (z == 2) ? Wv : Wo;
  unsigned short* out = WT + (size_t)z * 512 * 512;
  const int k0 = blockIdx.x * 64, n0 = blockIdx.y * 64;
  const int tid = threadIdx.x;
#pragma unroll
  for (int i = 0; i < 4; ++i) {
    int chunk = i * 256 + tid;
    int row = chunk >> 4, fc = chunk & 15;
    *(float4*)(T + row * 68 + fc * 4) =
        *(const float4*)(W + (size_t)(k0 + row) * 512 + n0 + fc * 4);
  }
  __syncthreads();
#pragma unroll
  for (int i = 0; i < 2; ++i) {
    int chunk = i * 256 + tid;
    int nr = chunk >> 3, kc = chunk & 7;
    u16x8 v;
#pragma unroll
    for (int j = 0; j < 8; ++j) v[j] = f2bf(T[(kc * 8 + j) * 68 + nr]);
    *(u16x8*)(out + (size_t)(n0 + nr) * 512 + k0 + kc * 8) = v;
  }
}

// ---- fused QKV GEMM v2: C[8192][1536] = [q|k|v] proj. 128x128 tile, BK=32,
// 16 K-steps, 4 waves x (64x64), 32 KB LDS (dbuf) -> 3 blocks/CU co-resident.
// m97-geometry: 16 MFMA per 8 ds_read_b128 per step (2:1), counted vmcnt(4). ----
__global__ __launch_bounds__(256) void gemm_qkv(const unsigned short* __restrict__ Aq,
                                                const unsigned short* __restrict__ Ak,
                                                const unsigned short* __restrict__ Av,
                                                const unsigned short* __restrict__ Bt,
                                                unsigned short* __restrict__ C,
                                                float qscale) {
  __shared__ __align__(16) unsigned short Abuf[2][128 * 32];
  __shared__ __align__(16) unsigned short Bbuf[2][128 * 32];
  const int K = 512, LDC = 1536;
  const unsigned short* A = (blockIdx.y < 4) ? Aq : (blockIdx.y < 8) ? Ak : Av;
  const float scale = (blockIdx.y < 4) ? qscale : 1.0f;
  const int tid = threadIdx.x;
  const int wid = tid >> 6, lane = tid & 63, quad = lane >> 4, li = lane & 15;
  const int bm = blockIdx.x * 128, bn = blockIdx.y * 128;
  const int wr = (wid >> 1) * 64, wc = (wid & 1) * 64;   // wave's 64x64 quadrant

  // staging: per thread 2 A-chunks + 2 B-chunks of 16B per step (128 rows x 4 chunks)
  const unsigned short* ga[2]; int oa[2];
  const unsigned short* gb[2]; int ob[2];
#pragma unroll
  for (int i = 0; i < 2; ++i) {
    int lam = i * 256 + tid;
    int r = lam >> 2, c = (lam & 3) ^ (r & 3);           // store linear, pre-swizzled src
    ga[i] = A + (size_t)(bm + r) * K + c * 8;
    gb[i] = Bt + (size_t)(bn + r) * K + c * 8;
    oa[i] = lam * 8;
    ob[i] = lam * 8;
  }
#pragma unroll
  for (int i = 0; i < 2; ++i) { gl2lds16(ga[i], &Abuf[0][oa[i]]); ga[i] += 32; }
#pragma unroll
  for (int i = 0; i < 2; ++i) { gl2lds16(gb[i], &Bbuf[0][ob[i]]); gb[i] += 32; }

  f32x4 acc[4][4] = {};
  const int xo = (quad ^ (li & 3)) * 8;                  // swizzled k-chunk offset
  for (int s = 0; s < 16; ++s) {
    __builtin_amdgcn_s_barrier();          // A: all waves done reading buf (s+1)&1
    if (s + 1 < 16) {
      int p = (s + 1) & 1;
#pragma unroll
      for (int i = 0; i < 2; ++i) { gl2lds16(ga[i], &Abuf[p][oa[i]]); ga[i] += 32; }
#pragma unroll
      for (int i = 0; i < 2; ++i) { gl2lds16(gb[i], &Bbuf[p][ob[i]]); gb[i] += 32; }
      asm volatile("s_waitcnt vmcnt(4)" ::: "memory");   // drain step s's loads only
    } else {
      asm volatile("s_waitcnt vmcnt(0)" ::: "memory");
    }
    __builtin_amdgcn_s_barrier();          // B: publish step s
    __builtin_amdgcn_sched_barrier(0);
    const unsigned short* As = &Abuf[s & 1][0];
    const unsigned short* Bs = &Bbuf[s & 1][0];
    bf16x8 af[4], bf[4];
#pragma unroll
    for (int t = 0; t < 4; ++t)
      af[t] = *(const bf16x8*)(As + (wr + t * 16 + li) * 32 + xo);
#pragma unroll
    for (int t = 0; t < 4; ++t)
      bf[t] = *(const bf16x8*)(Bs + (wc + t * 16 + li) * 32 + xo);
#pragma unroll
    for (int mt = 0; mt < 4; ++mt)
#pragma unroll
      for (int nt = 0; nt < 4; ++nt)
        acc[mt][nt] = __builtin_amdgcn_mfma_f32_16x16x32_bf16(af[mt], bf[nt], acc[mt][nt], 0, 0, 0);
  }
#pragma unroll
  for (int mt = 0; mt < 4; ++mt)
#pragma unroll
    for (int nt = 0; nt < 4; ++nt) {
      int r0 = bm + wr + mt * 16 + quad * 4;
      int c  = bn + wc + nt * 16 + li;
#pragma unroll
      for (int r = 0; r < 4; ++r)
        C[(size_t)(r0 + r) * LDC + c] = f2bf(acc[mt][nt][r] * scale);
    }
}

// ---- O-proj GEMM: out[8192][512] f32 = ob[8192][512] * WoT^T. (unchanged) ----
__global__ __launch_bounds__(256) void gemm_o(const unsigned short* __restrict__ A,
                                              const unsigned short* __restrict__ Bt,
                                              float* __restrict__ Cf) {
  __shared__ __align__(16) unsigned short Abuf[2][128 * 64];
  __shared__ __align__(16) unsigned short Bbuf[2][64 * 64];
  const int K = 512, LDC = 512;
  const int tid = threadIdx.x;
  const int wid = tid >> 6, lane = tid & 63, quad = lane >> 4, li = lane & 15;
  const int bm = blockIdx.x * 128, bn = blockIdx.y * 64;
  const int wm = wid * 32;
  const unsigned short* ga[4]; int oa[4];
  const unsigned short* gb[2]; int ob[2];
#pragma unroll
  for (int i = 0; i < 4; ++i) {
    int lam = i * 256 + wid * 64 + lane;
    int r = lam >> 3, c = (lam & 7) ^ (r & 7);
    ga[i] = A + (size_t)(bm + r) * K + c * 8;
    oa[i] = lam * 8;
  }
#pragma unroll
  for (int i = 0; i < 2; ++i) {
    int lam = i * 256 + wid * 64 + lane;
    int r = lam >> 3, c = (lam & 7) ^ (r & 7);
    gb[i] = Bt + (size_t)(bn + r) * K + c * 8;
    ob[i] = lam * 8;
  }
#pragma unroll
  for (int i = 0; i < 4; ++i) { gl2lds16(ga[i], &Abuf[0][oa[i]]); ga[i] += 64; }
#pragma unroll
  for (int i = 0; i < 2; ++i) { gl2lds16(gb[i], &Bbuf[0][ob[i]]); gb[i] += 64; }

  f32x4 acc[2][4] = {};
  const int sw = li & 7;
  for (int s = 0; s < 8; ++s) {
    __builtin_amdgcn_s_barrier();
    if (s + 1 < 8) {
      int p = (s + 1) & 1;
#pragma unroll
      for (int i = 0; i < 4; ++i) { gl2lds16(ga[i], &Abuf[p][oa[i]]); ga[i] += 64; }
#pragma unroll
      for (int i = 0; i < 2; ++i) { gl2lds16(gb[i], &Bbuf[p][ob[i]]); gb[i] += 64; }
      asm volatile("s_waitcnt vmcnt(6)" ::: "memory");
    } else {
      asm volatile("s_waitcnt vmcnt(0)" ::: "memory");
    }
    __builtin_amdgcn_s_barrier();
    __builtin_amdgcn_sched_barrier(0);
    const unsigned short* As = &Abuf[s & 1][0];
    const unsigned short* Bs = &Bbuf[s & 1][0];
#pragma unroll
    for (int kk = 0; kk < 2; ++kk) {
      bf16x8 af[2], bfr[4];
#pragma unroll
      for (int t = 0; t < 2; ++t)
        af[t] = *(const bf16x8*)(As + (wm + t * 16 + li) * 64 + (((kk * 4 + quad) ^ sw) * 8));
#pragma unroll
      for (int t = 0; t < 4; ++t)
        bfr[t] = *(const bf16x8*)(Bs + (t * 16 + li) * 64 + (((kk * 4 + quad) ^ sw) * 8));
#pragma unroll
      for (int mt = 0; mt < 2; ++mt)
#pragma unroll
        for (int nt = 0; nt < 4; ++nt)
          acc[mt][nt] = __builtin_amdgcn_mfma_f32_16x16x32_bf16(af[mt], bfr[nt], acc[mt][nt], 0, 0, 0);
    }
  }
#pragma unroll
  for (int mt = 0; mt < 2; ++mt)
#pragma unroll
    for (int nt = 0; nt < 4; ++nt) {
      int r0 = bm + wm + mt * 16 + quad * 4;
      int c  = bn + nt * 16 + li;
#pragma unroll
      for (int r = 0; r < 4; ++r)
        Cf[(size_t)(r0 + r) * LDC + c] = acc[mt][nt][r];
    }
}

// ---- qkvh V-section -> vt [(b*8+h)*64+d][4096], with tau-permuted keys per 64-tile ----
// tau(p) = (p&32) | k<<4 | q<<2 | r   where p&31 = [q1 q0 k r1 r0]
// P.V is invariant under a shared key permutation; tau makes the S^T lane layout
// (keys kb*16+quad*4+r) directly usable as the PV A-fragment with NO P LDS round-trip.
__global__ __launch_bounds__(256) void vtrans(const unsigned short* __restrict__ qkv,
                                              unsigned short* __restrict__ vt) {
  __shared__ __align__(16) unsigned short T[64 * 72];
  const int kt = blockIdx.x;
  const int bh = blockIdx.y;
  const int b = bh >> 3, h = bh & 7;
  const int tid = threadIdx.x;
#pragma unroll
  for (int i = 0; i < 2; ++i) {
    int chunk = i * 256 + tid;
    int row = chunk >> 3, c8 = chunk & 7;
    *(uint4*)(T + row * 72 + c8 * 8) =
        *(const uint4*)(qkv + (size_t)(b * 4096 + kt * 64 + row) * 1536 + 1024 + h * 64 + c8 * 8);
  }
  __syncthreads();
#pragma unroll
  for (int i = 0; i < 2; ++i) {
    int chunk = i * 256 + tid;
    int dr = chunk >> 3, c8 = chunk & 7;
    u16x8 v;
#pragma unroll
    for (int j = 0; j < 8; ++j) {
      int p = c8 * 8 + j;
      int ph = p & 31;
      int lk = (p & 32) | (((ph >> 2) & 1) << 4) | (((ph >> 3) & 3) << 2) | (ph & 3);
      v[j] = T[lk * 72 + dr];
    }
    *(u16x8*)(vt + (size_t)(bh * 64 + dr) * 4096 + kt * 64 + c8 * 8) = v;
  }
}

// ---- flash attention v5 (unchanged from R5, verified 94.4 us): in-block split-KV,
// 8 waves x 32q, NO-MAX softmax, LDS combine, in-register P via tau-permuted V. ----
__global__ __launch_bounds__(512, 2) void attn(const unsigned short* __restrict__ qkv,
                                               const unsigned short* __restrict__ vt,
                                               const int* __restrict__ mask,
                                               unsigned short* __restrict__ obuf) {
  // SM layout (shorts): Kb [par][hv][4096] = 16384 | Vb same = 16384 | Msk 256
  __shared__ __align__(16) unsigned short SM[33024];
  unsigned short* Kb = SM;
  unsigned short* Vb = SM + 16384;
  unsigned short* Mk = SM + 32768;
  const int qt = blockIdx.x, h = blockIdx.y, b = blockIdx.z;
  const int tid = threadIdx.x;
  const int wid = tid >> 6, lane = tid & 63, quad = lane >> 4, li = lane & 15;
  const int hv = wid >> 2;   // which KV half this wave computes
  const int wq = wid & 3;    // query group of 32
  const size_t tok0 = (size_t)b * 4096;

  if (tid < 256) {
    const int4* mp = (const int4*)(mask + b * 4096 + tid * 16);
    unsigned int bits = 0;
#pragma unroll
    for (int j = 0; j < 4; ++j) {
      int4 m4 = mp[j];
      bits |= (m4.x ? 1u : 0u) << (j * 4 + 0);
      bits |= (m4.y ? 1u : 0u) << (j * 4 + 1);
      bits |= (m4.z ? 1u : 0u) << (j * 4 + 2);
      bits |= (m4.w ? 1u : 0u) << (j * 4 + 3);
    }
    Mk[tid] = (unsigned short)bits;
  }

  // Q as B-operand: wave owns queries qt*128 + wq*32 + qg*16 + li (qg = 0,1)
  const unsigned short* qp0 = qkv + (tok0 + qt * 128 + wq * 32 + li) * 1536 + h * 64;
  const unsigned short* qp1 = qp0 + (size_t)16 * 1536;
  bf16x8 bq[2][2];
  bq[0][0] = *(const bf16x8*)(qp0 + quad * 8);
  bq[0][1] = *(const bf16x8*)(qp0 + 32 + quad * 8);
  bq[1][0] = *(const bf16x8*)(qp1 + quad * 8);
  bq[1][1] = *(const bf16x8*)(qp1 + 32 + quad * 8);

  // staging: all 512 threads; each stages 1 chunk of each of {K0,K1,V0,V1} per step
  const unsigned short* kbase = qkv + tok0 * 1536 + 512 + h * 64;
  const unsigned short* vbase = vt + (size_t)(b * 8 + h) * 64 * 4096;
  const int sr = tid >> 3, sc8 = ((tid & 7) ^ (sr & 7)) * 8;
  const unsigned short* gk0 = kbase + (size_t)sr * 1536 + sc8;                  // half 0
  const unsigned short* gk1 = kbase + (size_t)(2048 + sr) * 1536 + sc8;         // half 1
  const unsigned short* gv0 = vbase + (size_t)sr * 4096 + sc8;                  // half 0
  const unsigned short* gv1 = vbase + (size_t)sr * 4096 + 2048 + sc8;           // half 1
  const int ol = tid * 8;   // short offset of this thread's chunk within a tile

  gl2lds16(gk0, Kb + ol);          gl2lds16(gk1, Kb + 4096 + ol);
  gl2lds16(gv0, Vb + ol);          gl2lds16(gv1, Vb + 4096 + ol);
  gk0 += (size_t)64 * 1536; gk1 += (size_t)64 * 1536; gv0 += 64; gv1 += 64;

  f32x4 lacc[2] = {};
  f32x4 accO[2][4] = {};
  const int sw = li & 7;

  // publish Mk before first raw barrier (raw s_barrier doesn't drain lgkm)
  asm volatile("s_waitcnt lgkmcnt(0)" ::: "memory");

  for (int t = 0; t < 32; ++t) {
    __builtin_amdgcn_s_barrier();          // A: all waves done with buf (t+1)&1
    if (t < 31) {
      int p = (t + 1) & 1;
      unsigned short* kd = Kb + p * 8192;
      unsigned short* vd = Vb + p * 8192;
      gl2lds16(gk0, kd + ol);        gl2lds16(gk1, kd + 4096 + ol);
      gl2lds16(gv0, vd + ol);        gl2lds16(gv1, vd + 4096 + ol);
      gk0 += (size_t)64 * 1536; gk1 += (size_t)64 * 1536; gv0 += 64; gv1 += 64;
      asm volatile("s_waitcnt vmcnt(4)" ::: "memory");  // drain step t's loads only
    } else {
      asm volatile("s_waitcnt vmcnt(0)" ::: "memory");
    }
    __builtin_amdgcn_s_barrier();          // B: publish step t
    __builtin_amdgcn_sched_barrier(0);
    const unsigned short* Ks = Kb + (t & 1) * 8192 + hv * 4096;
    const unsigned short* Vs = Vb + (t & 1) * 8192 + hv * 4096;

    // S^T = K Q^T: lane = query li; keys kb*16 + quad*4 + r; K reads shared by both qg
    f32x4 s[2][4];
    __builtin_amdgcn_s_setprio(1);
#pragma unroll
    for (int kb = 0; kb < 4; ++kb) {
      const unsigned short* kr = Ks + (kb * 16 + li) * 64;
      bf16x8 ak0 = *(const bf16x8*)(kr + ((quad ^ sw) * 8));
      bf16x8 ak1 = *(const bf16x8*)(kr + (((4 + quad) ^ sw) * 8));
#pragma unroll
      for (int qg = 0; qg < 2; ++qg) {
        f32x4 z = {};
        z = __builtin_amdgcn_mfma_f32_16x16x32_bf16(ak0, bq[qg][0], z, 0, 0, 0);
        z = __builtin_amdgcn_mfma_f32_16x16x32_bf16(ak1, bq[qg][1], z, 0, 0, 0);
        s[qg][kb] = z;
      }
    }
    __builtin_amdgcn_s_setprio(0);
    int tt = hv * 32 + t;
    unsigned long long mbits = *(const unsigned long long*)(Mk + tt * 4);
    if (mbits != ~0ull) {
#pragma unroll
      for (int kb = 0; kb < 4; ++kb)
#pragma unroll
        for (int r = 0; r < 4; ++r) {
          int key = kb * 16 + quad * 4 + r;
          if (!((mbits >> key) & 1ull)) { s[0][kb][r] = -1e30f; s[1][kb][r] = -1e30f; }
        }
    }
    // p = exp2(s); partial l; pack in-register into PV A-fragments (tau-aligned)
    bf16x8 pf[2][2];
#pragma unroll
    for (int qg = 0; qg < 2; ++qg) {
#pragma unroll
      for (int kb = 0; kb < 4; ++kb) {
#pragma unroll
        for (int r = 0; r < 4; ++r) s[qg][kb][r] = __builtin_amdgcn_exp2f(s[qg][kb][r]);
        lacc[qg] += s[qg][kb];
      }
      uint4 u0, u1;
      u0.x = cvtpk(s[qg][0][0], s[qg][0][1]); u0.y = cvtpk(s[qg][0][2], s[qg][0][3]);
      u0.z = cvtpk(s[qg][1][0], s[qg][1][1]); u0.w = cvtpk(s[qg][1][2], s[qg][1][3]);
      u1.x = cvtpk(s[qg][2][0], s[qg][2][1]); u1.y = cvtpk(s[qg][2][2], s[qg][2][3]);
      u1.z = cvtpk(s[qg][3][0], s[qg][3][1]); u1.w = cvtpk(s[qg][3][2], s[qg][3][3]);
      pf[qg][0] = __builtin_bit_cast(bf16x8, u0);
      pf[qg][1] = __builtin_bit_cast(bf16x8, u1);
    }
    // O += P V ; V reads shared by both qg
    __builtin_amdgcn_s_setprio(1);
#pragma unroll
    for (int dc = 0; dc < 4; ++dc) {
      const unsigned short* vr = Vs + (dc * 16 + li) * 64;
      bf16x8 bv0 = *(const bf16x8*)(vr + ((quad ^ sw) * 8));
      bf16x8 bv1 = *(const bf16x8*)(vr + (((4 + quad) ^ sw) * 8));
#pragma unroll
      for (int qg = 0; qg < 2; ++qg) {
        accO[qg][dc] = __builtin_amdgcn_mfma_f32_16x16x32_bf16(pf[qg][0], bv0, accO[qg][dc], 0, 0, 0);
        accO[qg][dc] = __builtin_amdgcn_mfma_f32_16x16x32_bf16(pf[qg][1], bv1, accO[qg][dc], 0, 0, 0);
      }
    }
    __builtin_amdgcn_s_setprio(0);
  }

  // ---- combine halves: waves 4-7 dump partials to LDS; waves 0-3 add + store ----
  __syncthreads();                       // K/V buffers dead; reuse as f32 scratch (40 KB)
  float* scr = (float*)SM;               // layout: scr[j*256 + wq*64 + lane], j in 0..39
  if (hv == 1) {
#pragma unroll
    for (int qg = 0; qg < 2; ++qg) {
#pragma unroll
      for (int dc = 0; dc < 4; ++dc)
#pragma unroll
        for (int r = 0; r < 4; ++r)
          scr[(qg * 16 + dc * 4 + r) * 256 + wq * 64 + lane] = accO[qg][dc][r];
#pragma unroll
      for (int r = 0; r < 4; ++r)
        scr[(32 + qg * 4 + r) * 256 + wq * 64 + lane] = lacc[qg][r];
    }
  }
  __syncthreads();
  if (hv == 0) {
#pragma unroll
    for (int qg = 0; qg < 2; ++qg) {
#pragma unroll
      for (int dc = 0; dc < 4; ++dc)
#pragma unroll
        for (int r = 0; r < 4; ++r)
          accO[qg][dc][r] += scr[(qg * 16 + dc * 4 + r) * 256 + wq * 64 + lane];
#pragma unroll
      for (int r = 0; r < 4; ++r)
        lacc[qg][r] += scr[(32 + qg * 4 + r) * 256 + wq * 64 + lane];
    }
    // full l per query, then normalize + store
#pragma unroll
    for (int qg = 0; qg < 2; ++qg) {
      float lt = lacc[qg][0] + lacc[qg][1] + lacc[qg][2] + lacc[qg][3];
      lt += __shfl_xor(lt, 16);
      lt += __shfl_xor(lt, 32);
      float lv0 = 1.f / __shfl(lt, quad * 4 + 0);
      float lv1 = 1.f / __shfl(lt, quad * 4 + 1);
      float lv2 = 1.f / __shfl(lt, quad * 4 + 2);
      float lv3 = 1.f / __shfl(lt, quad * 4 + 3);
      size_t r0q = tok0 + qt * 128 + wq * 32 + qg * 16 + quad * 4;
#pragma unroll
      for (int dc = 0; dc < 4; ++dc) {
        size_t col = h * 64 + dc * 16 + li;
        obuf[(r0q + 0) * 512 + col] = f2bf(accO[qg][dc][0] * lv0);
        obuf[(r0q + 1) * 512 + col] = f2bf(accO[qg][dc][1] * lv1);
        obuf[(r0q + 2) * 512 + col] = f2bf(accO[qg][dc][2] * lv2);
        obuf[(r0q + 3) * 512 + col] = f2bf(accO[qg][dc][3] * lv3);
      }
    }
  }
}

extern "C" void kernel_launch(void* const* d_in, const int* in_sizes, int n_in,
                              void* d_out, int out_size, void* d_ws, size_t ws_size,
                              hipStream_t stream) {
  const float* q  = (const float*)d_in[0];
  const float* k  = (const float*)d_in[1];
  const float* v  = (const float*)d_in[2];
  const int* mask = (const int*)d_in[3];
  const float* Wq = (const float*)d_in[4];
  const float* Wk = (const float*)d_in[5];
  const float* Wv = (const float*)d_in[6];
  const float* Wo = (const float*)d_in[7];
  float* out = (float*)d_out;

  char* ws = (char*)d_ws;
  const size_t SA = (size_t)8192 * 512 * 2;   // 8 MB
  unsigned short* qbf  = (unsigned short*)(ws);
  unsigned short* kbf  = (unsigned short*)(ws + SA);
  unsigned short* vbf  = (unsigned short*)(ws + 2 * SA);
  unsigned short* qkvh = (unsigned short*)(ws + 3 * SA);          // 24 MB
  unsigned short* wAll = (unsigned short*)(ws + 6 * SA);          // 2 MB
  unsigned short* woT  = wAll + (size_t)3 * 512 * 512;
  unsigned short* vtb  = qbf;  // dead after gemm_qkv
  unsigned short* ob   = kbf;  // dead after gemm_qkv

  dim3 cg(2048, 3);
  cvt3<<<cg, 256, 0, stream>>>(q, k, v, qbf, kbf, vbf);
  dim3 wg(8, 8, 4);
  wtrans4<<<wg, 256, 0, stream>>>(Wq, Wk, Wv, Wo, wAll);
  const float qscale = 0.125f * 1.44269504f;  // 1/sqrt(64) * log2(e)
  dim3 gq(64, 12);
  gemm_qkv<<<gq, 256, 0, stream>>>(qbf, kbf, vbf, wAll, qkvh, qscale);
  dim3 vg(64, 16);
  vtrans<<<vg, 256, 0, stream>>>(qkvh, vtb);
  dim3 ag(32, 8, 2);
  attn<<<ag, 512, 0, stream>>>(qkvh, vtb, mask, ob);
  dim3 go(64, 8);
  gemm_o<<<go, 256, 0, stream>>>(ob, woT, out);
}